// Round 1
// baseline (10058.921 us; speedup 1.0000x reference)
//
#include <hip/hip_runtime.h>
#include <hip/hip_bf16.h>

#define E_TOT  6572
#define E4_TOT 1643

// One thread = one point. Fully unrolled so h[] / h1[] stay in registers
// (runtime-indexed arrays would go to scratch). Weights are wave-uniform
// -> compiler emits scalar loads (L2-resident, overlapped with VALU).
__global__ void Model_85744727097983_kernel(
    const float* __restrict__ x,       // [N,2]
    const float* __restrict__ emb,     // [N]
    const float* __restrict__ em0_w,   // [E,20]
    const float* __restrict__ em1_w,   // [E4,44]
    const float* __restrict__ W0,      // [66,128]
    const float* __restrict__ b0,      // [128]
    const float* __restrict__ W1,      // [128,96]
    const float* __restrict__ b1,      // [96]
    const float* __restrict__ W2,      // [96]
    const float* __restrict__ b2,      // [1]
    float* __restrict__ out,           // [N]
    int N)
{
    const int n = blockIdx.x * 256 + threadIdx.x;
    if (n >= N) return;

    // ---------------- feature build: h[66] = [x(2), em0(20), em1(44)] ----
    float h[66];
    {
        float2 xv = reinterpret_cast<const float2*>(x)[n];
        h[0] = xv.x; h[1] = xv.y;
    }
    const float t  = emb[n];
    const int   i0 = (int)t;                       // trunc == floor (t>=0)
    const int   i1 = min(i0 + 1, E_TOT - 1);
    const float p  = t - (float)i0;
    {
        // row stride 20 floats = 80 B -> 16B aligned, float4-loadable
        const float4* r0 = reinterpret_cast<const float4*>(em0_w + i0 * 20);
        const float4* r1 = reinterpret_cast<const float4*>(em0_w + i1 * 20);
        #pragma unroll
        for (int v = 0; v < 5; ++v) {
            float4 a = r0[v], b = r1[v];
            h[2 + 4 * v + 0] = fmaf(p, b.x - a.x, a.x);
            h[2 + 4 * v + 1] = fmaf(p, b.y - a.y, a.y);
            h[2 + 4 * v + 2] = fmaf(p, b.z - a.z, a.z);
            h[2 + 4 * v + 3] = fmaf(p, b.w - a.w, a.w);
        }
    }
    const float t4 = t * 0.25f;                    // exact in fp32
    const int   j0 = (int)t4;
    const int   j1 = min(j0 + 1, E4_TOT - 1);      // clamp matters at the top
    const float q  = t4 - (float)j0;
    {
        // row stride 44 floats = 176 B -> 16B aligned
        const float4* r0 = reinterpret_cast<const float4*>(em1_w + j0 * 44);
        const float4* r1 = reinterpret_cast<const float4*>(em1_w + j1 * 44);
        #pragma unroll
        for (int v = 0; v < 11; ++v) {
            float4 a = r0[v], b = r1[v];
            h[22 + 4 * v + 0] = fmaf(q, b.x - a.x, a.x);
            h[22 + 4 * v + 1] = fmaf(q, b.y - a.y, a.y);
            h[22 + 4 * v + 2] = fmaf(q, b.z - a.z, a.z);
            h[22 + 4 * v + 3] = fmaf(q, b.w - a.w, a.w);
        }
    }

    // ---------------- layer 0: [66] -> [128], clamp(0,1) -----------------
    float h1[128];
    #pragma unroll
    for (int o = 0; o < 128; ++o) h1[o] = b0[o];
    #pragma unroll
    for (int k = 0; k < 66; ++k) {
        const float hk = h[k];
        const float* w = W0 + k * 128;             // contiguous per k
        #pragma unroll
        for (int o = 0; o < 128; ++o) h1[o] = fmaf(hk, w[o], h1[o]);
    }
    #pragma unroll
    for (int o = 0; o < 128; ++o) h1[o] = fminf(fmaxf(h1[o], 0.0f), 1.0f);

    // ---------------- layer 1: [128] -> [96], clamp; layer 2 fused -------
    float z = b2[0];
    #pragma unroll
    for (int ob = 0; ob < 96; ob += 4) {           // 4 indep acc chains (ILP)
        float a0 = b1[ob + 0], a1 = b1[ob + 1];
        float a2 = b1[ob + 2], a3 = b1[ob + 3];
        #pragma unroll
        for (int k = 0; k < 128; ++k) {
            const float hk = h1[k];
            const float* w = W1 + k * 96 + ob;
            a0 = fmaf(hk, w[0], a0);
            a1 = fmaf(hk, w[1], a1);
            a2 = fmaf(hk, w[2], a2);
            a3 = fmaf(hk, w[3], a3);
        }
        a0 = fminf(fmaxf(a0, 0.0f), 1.0f);
        a1 = fminf(fmaxf(a1, 0.0f), 1.0f);
        a2 = fminf(fmaxf(a2, 0.0f), 1.0f);
        a3 = fminf(fmaxf(a3, 0.0f), 1.0f);
        z = fmaf(a0, W2[ob + 0], z);
        z = fmaf(a1, W2[ob + 1], z);
        z = fmaf(a2, W2[ob + 2], z);
        z = fmaf(a3, W2[ob + 3], z);
    }

    out[n] = 1.0f / (1.0f + __expf(-z));
}

extern "C" void kernel_launch(void* const* d_in, const int* in_sizes, int n_in,
                              void* d_out, int out_size, void* d_ws, size_t ws_size,
                              hipStream_t stream) {
    const float* x     = (const float*)d_in[0];
    const float* emb   = (const float*)d_in[1];
    const float* em0_w = (const float*)d_in[2];
    const float* em1_w = (const float*)d_in[3];
    const float* W0    = (const float*)d_in[4];
    const float* b0    = (const float*)d_in[5];
    const float* W1    = (const float*)d_in[6];
    const float* b1    = (const float*)d_in[7];
    const float* W2    = (const float*)d_in[8];
    const float* b2    = (const float*)d_in[9];
    float* out = (float*)d_out;

    const int N = in_sizes[1];                     // embeddings count = 1e6
    const int blocks = (N + 255) / 256;
    Model_85744727097983_kernel<<<blocks, 256, 0, stream>>>(
        x, emb, em0_w, em1_w, W0, b0, W1, b1, W2, b2, out, N);
}

// Round 3
// 104.976 us; speedup vs baseline: 95.8209x; 95.8209x over previous
//
#include <hip/hip_runtime.h>
#include <hip/hip_bf16.h>

typedef short bf16x8 __attribute__((ext_vector_type(8)));
typedef float f32x4  __attribute__((ext_vector_type(4)));

#define E_TOT   6572
#define E4_TOT  1643
#define RS_B    288     // LDS row stride bytes (144 halfwords; 72 dwords -> good bank spread)
#define ROWS    128     // points per block (2 waves x 64 rows)

static __device__ __forceinline__ unsigned short bf16b(float f) {
    union { float f; unsigned u; } v; v.f = f;
    return (unsigned short)((v.u + 0x7FFFu + ((v.u >> 16) & 1u)) >> 16);  // RNE
}
static __device__ __forceinline__ unsigned pk2(float a, float b) {
    return (unsigned)bf16b(a) | ((unsigned)bf16b(b) << 16);
}
static __device__ __forceinline__ float b2f(short h) {
    union { unsigned u; float f; } v; v.u = ((unsigned)(unsigned short)h) << 16;
    return v.f;
}

// Pre-pack W0/W1 (fp32) into bf16 MFMA B-fragment order:
//   frag(t,s), lane l, elem e  <-  W[k = 32s + 8*(l>>4) + e][n = 16t + (l&15)]
// W0 is padded K 66->96; rows k=0,1 (the x columns) are zeroed here and
// handled in fp32 in the main kernel's epilogue (precision).
__global__ void pack_w(const float* __restrict__ W0, const float* __restrict__ W1,
                       unsigned short* __restrict__ W0p, unsigned short* __restrict__ W1p)
{
    int id = blockIdx.x * 256 + threadIdx.x;      // [0, 24576)
    int e = id & 7, l = (id >> 3) & 63, f = id >> 9;
    int g = l >> 4, c = l & 15;
    if (f < 24) {                                 // W0p: f = t*3 + s, t<8, s<3
        int s = f % 3, t = f / 3;
        int k = s * 32 + g * 8 + e, n = t * 16 + c;
        float v = (k >= 2 && k < 66) ? W0[k * 128 + n] : 0.0f;
        W0p[id] = bf16b(v);
    } else {                                      // W1p: f-24 = t*4 + s, t<6, s<4
        int f1 = f - 24;
        int s = f1 & 3, t = f1 >> 2;
        int k = s * 32 + g * 8 + e, n = t * 16 + c;
        W1p[id - 12288] = bf16b(W1[k * 96 + n]);
    }
}

__global__ __launch_bounds__(128, 2) void fused_mlp(
    const float* __restrict__ x, const float* __restrict__ emb,
    const float* __restrict__ em0_w, const float* __restrict__ em1_w,
    const float* __restrict__ W0, const float* __restrict__ b0,
    const float* __restrict__ b1,
    const float* __restrict__ W2, const float* __restrict__ b2,
    const unsigned short* __restrict__ W0p, const unsigned short* __restrict__ W1p,
    float* __restrict__ out, int N)
{
    __shared__ char smem[ROWS * RS_B];            // 36864 B; reused hA -> h1 -> h2
    const int tid  = threadIdx.x;
    const int lane = tid & 63;
    const int wv   = tid >> 6;                    // wave 0/1; wave rows = [64*wv, 64*wv+64)
    const int g    = lane >> 4, c = lane & 15;
    const int p    = blockIdx.x * ROWS + tid;
    const int pc   = min(p, N - 1);               // tail: compute dup, guard store

    // ---------------- Phase A: build feature row `tid` (bf16), x kept fp32 --
    {
        unsigned* rw = (unsigned*)(smem + tid * RS_B);
        const float t  = emb[pc];
        const int   i0 = (int)t;                  // i0 <= 6570, so i0+1 in range
        const float pf = t - (float)i0;
        const float t4 = t * 0.25f;               // exact
        const int   j0 = (int)t4;
        const int   j1 = min(j0 + 1, E4_TOT - 1);
        const float qf = t4 - (float)j0;
        rw[0] = 0u;                               // cols 0,1 (x) zero in bf16 path
        const float4* r0 = (const float4*)(em0_w + i0 * 20);
        const float4* r1 = (const float4*)(em0_w + i0 * 20 + 20);
        #pragma unroll
        for (int v = 0; v < 5; ++v) {             // em0 -> cols 2..21
            float4 a = r0[v], b = r1[v];
            rw[1 + 2*v] = pk2(fmaf(pf, b.x-a.x, a.x), fmaf(pf, b.y-a.y, a.y));
            rw[2 + 2*v] = pk2(fmaf(pf, b.z-a.z, a.z), fmaf(pf, b.w-a.w, a.w));
        }
        const float4* s0 = (const float4*)(em1_w + j0 * 44);
        const float4* s1 = (const float4*)(em1_w + j1 * 44);
        #pragma unroll
        for (int v = 0; v < 11; ++v) {            // em1 -> cols 22..65
            float4 a = s0[v], b = s1[v];
            rw[11 + 2*v] = pk2(fmaf(qf, b.x-a.x, a.x), fmaf(qf, b.y-a.y, a.y));
            rw[12 + 2*v] = pk2(fmaf(qf, b.z-a.z, a.z), fmaf(qf, b.w-a.w, a.w));
        }
        #pragma unroll
        for (int d = 33; d < 48; ++d) rw[d] = 0u; // K-pad 66..95 (avoid NaN*0)
        const float2 xv = *(const float2*)(x + 2 * pc);
        ((float*)rw)[48] = xv.x;                  // fp32 x stashed at byte 192
        ((float*)rw)[49] = xv.y;
    }
    __syncthreads();

    // ---------------- Layer 0: h[96] @ W0p -> h1[128], clamp ---------------
    // A-frag: lane holds row (l&15), k = 8*(l>>4)+e  (m97-verified layout)
    const char* arow = smem + (wv * 64 + c) * RS_B + g * 16;
    bf16x8 a0[4][3];
    #pragma unroll
    for (int mt = 0; mt < 4; ++mt)
        #pragma unroll
        for (int s = 0; s < 3; ++s)
            a0[mt][s] = *(const bf16x8*)(arow + mt * 16 * RS_B + s * 64);

    float2 xp[4][4];                              // fp32 x for this lane's D rows
    #pragma unroll
    for (int mt = 0; mt < 4; ++mt)
        #pragma unroll
        for (int r = 0; r < 4; ++r)
            xp[mt][r] = *(const float2*)(smem + (wv*64 + mt*16 + g*4 + r) * RS_B + 192);

    #pragma unroll
    for (int t = 0; t < 8; ++t) {                 // 8 N-tiles of 16 (128 outs)
        bf16x8 bw[3];
        #pragma unroll
        for (int s = 0; s < 3; ++s)
            bw[s] = *(const bf16x8*)(W0p + ((t*3 + s) << 9) + (lane << 3));
        f32x4 acc[4] = {};
        #pragma unroll
        for (int s = 0; s < 3; ++s)
            #pragma unroll
            for (int mt = 0; mt < 4; ++mt)
                acc[mt] = __builtin_amdgcn_mfma_f32_16x16x32_bf16(a0[mt][s], bw[s], acc[mt], 0, 0, 0);
        const float w00 = W0[t*16 + c];           // W0[0][n], fp32 x fix-up
        const float w01 = W0[128 + t*16 + c];     // W0[1][n]
        const float bb  = b0[t*16 + c];
        #pragma unroll
        for (int mt = 0; mt < 4; ++mt)
            #pragma unroll
            for (int r = 0; r < 4; ++r) {
                float v = acc[mt][r] + bb + xp[mt][r].x * w00 + xp[mt][r].y * w01;
                v = fminf(fmaxf(v, 0.0f), 1.0f);
                // D layout: row = (l>>4)*4 + r, col = l&15 (m89-verified)
                *(unsigned short*)(smem + (wv*64 + mt*16 + g*4 + r) * RS_B + (t*16 + c) * 2) = bf16b(v);
            }
    }

    // ---------------- Layer 1: h1[128] @ W1p -> h2[96], clamp --------------
    bf16x8 a1[4][4];                              // load all h1 frags before h2 clobbers
    #pragma unroll
    for (int mt = 0; mt < 4; ++mt)
        #pragma unroll
        for (int s = 0; s < 4; ++s)
            a1[mt][s] = *(const bf16x8*)(arow + mt * 16 * RS_B + s * 64);

    #pragma unroll
    for (int t = 0; t < 6; ++t) {                 // 6 N-tiles of 16 (96 outs)
        bf16x8 bw[4];
        #pragma unroll
        for (int s = 0; s < 4; ++s)
            bw[s] = *(const bf16x8*)(W1p + ((t*4 + s) << 9) + (lane << 3));
        f32x4 acc[4] = {};
        #pragma unroll
        for (int s = 0; s < 4; ++s)
            #pragma unroll
            for (int mt = 0; mt < 4; ++mt)
                acc[mt] = __builtin_amdgcn_mfma_f32_16x16x32_bf16(a1[mt][s], bw[s], acc[mt], 0, 0, 0);
        const float bb = b1[t*16 + c];
        #pragma unroll
        for (int mt = 0; mt < 4; ++mt)
            #pragma unroll
            for (int r = 0; r < 4; ++r) {
                float v = acc[mt][r] + bb;
                v = fminf(fmaxf(v, 0.0f), 1.0f);
                *(unsigned short*)(smem + (wv*64 + mt*16 + g*4 + r) * RS_B + (t*16 + c) * 2) = bf16b(v);
            }
    }
    __syncthreads();

    // ---------------- Layer 2 + sigmoid (per thread, own row) --------------
    {
        const char* rowp = smem + tid * RS_B;
        float z = b2[0];
        #pragma unroll
        for (int c2 = 0; c2 < 12; ++c2) {         // 96 h2 values = 12 x bf16x8
            bf16x8 hb = *(const bf16x8*)(rowp + c2 * 16);
            #pragma unroll
            for (int e = 0; e < 8; ++e)
                z = fmaf(b2f(hb[e]), W2[c2*8 + e], z);   // W2 wave-uniform -> s_load
        }
        z = 1.0f / (1.0f + __expf(-z));
        if (p < N) out[p] = z;
    }
}

extern "C" void kernel_launch(void* const* d_in, const int* in_sizes, int n_in,
                              void* d_out, int out_size, void* d_ws, size_t ws_size,
                              hipStream_t stream) {
    const float* x     = (const float*)d_in[0];
    const float* emb   = (const float*)d_in[1];
    const float* em0_w = (const float*)d_in[2];
    const float* em1_w = (const float*)d_in[3];
    const float* W0    = (const float*)d_in[4];
    const float* b0    = (const float*)d_in[5];
    const float* W1    = (const float*)d_in[6];
    const float* b1    = (const float*)d_in[7];
    const float* W2    = (const float*)d_in[8];
    const float* b2    = (const float*)d_in[9];
    float* out = (float*)d_out;
    const int N = in_sizes[1];

    unsigned short* W0p = (unsigned short*)d_ws;   // 12288 bf16 = 24576 B
    unsigned short* W1p = W0p + 12288;             // 12288 bf16 = 24576 B

    pack_w<<<96, 256, 0, stream>>>(W0, W1, W0p, W1p);
    const int nb = (N + ROWS - 1) / ROWS;
    fused_mlp<<<nb, ROWS, 0, stream>>>(x, emb, em0_w, em1_w, W0, b0, b1, W2, b2,
                                       W0p, W1p, out, N);
}

// Round 4
// 95.092 us; speedup vs baseline: 105.7812x; 1.1039x over previous
//
#include <hip/hip_runtime.h>
#include <hip/hip_bf16.h>

typedef short bf16x8 __attribute__((ext_vector_type(8)));
typedef float f32x4  __attribute__((ext_vector_type(4)));

#define E4_TOT  1643
#define RS_B    272     // 68 dwords == 4 mod 32 -> b128 rows hit distinct bank groups
#define ROWS    128     // 2 waves x 64 points

static __device__ __forceinline__ unsigned pkrn(float a, float b) {
    union { __hip_bfloat162 h; unsigned u; } v;
    v.h = __float22bfloat162_rn(float2{a, b});    // compiler -> v_cvt_pk_bf16_f32
    return v.u;
}

// Pack W0/W1 (fp32) into bf16 MFMA B-fragment order:
//   frag(t,s), lane l, elem e  <-  W[k = 32s + 8*(l>>4) + e][n = 16t + (l&15)]
// W0 K padded 66->96. Dekker-x: rows 66,67 duplicate W0 rows 0,1 (x-lo term).
__global__ void pack_w(const float* __restrict__ W0, const float* __restrict__ W1,
                       unsigned short* __restrict__ W0p, unsigned short* __restrict__ W1p)
{
    int id = blockIdx.x * 256 + threadIdx.x;      // [0, 24576)
    int e = id & 7, l = (id >> 3) & 63, f = id >> 9;
    int g = l >> 4, c = l & 15;
    union { __hip_bfloat16 h; unsigned short u; } cv;
    if (f < 24) {                                 // W0p: f = t*3 + s, t<8, s<3
        int s = f % 3, t = f / 3;
        int k = s * 32 + g * 8 + e, n = t * 16 + c;
        float v = (k < 66) ? W0[k * 128 + n]
                : ((k < 68) ? W0[(k - 66) * 128 + n] : 0.0f);
        cv.h = __float2bfloat16(v);
        W0p[id] = cv.u;
    } else {                                      // W1p: f-24 = t*4 + s, t<6, s<4
        int f1 = f - 24;
        int s = f1 & 3, t = f1 >> 2;
        int k = s * 32 + g * 8 + e, n = t * 16 + c;
        cv.h = __float2bfloat16(W1[k * 96 + n]);
        W1p[id - 12288] = cv.u;
    }
}

__global__ __launch_bounds__(128, 2) void fused_mlp(
    const float* __restrict__ x, const float* __restrict__ emb,
    const float* __restrict__ em0_w, const float* __restrict__ em1_w,
    const float* __restrict__ b0, const float* __restrict__ b1,
    const float* __restrict__ W2, const float* __restrict__ b2,
    const unsigned short* __restrict__ W0p, const unsigned short* __restrict__ W1p,
    float* __restrict__ out, int N)
{
    __shared__ __align__(16) char smem[ROWS * RS_B];   // 34816 B; features -> h1
    const int tid  = threadIdx.x;
    const int lane = tid & 63;
    const int wv   = tid >> 6;
    const int g    = lane >> 4, c = lane & 15;
    const int p    = blockIdx.x * ROWS + tid;
    const int pc   = min(p, N - 1);               // tail: dup compute, guard store

    // ---- Phase A: build feature row in regs, store as 12 ds_write_b128 ----
    // hw layout: [0,1]=bf16(x) [2..21]=em0 [22..65]=em1 [66,67]=x_lo [68..95]=0
    {
        unsigned d[36];
        const float t  = emb[pc];
        const int   i0 = (int)t;                  // i0+1 <= E-1 always
        const float pf = t - (float)i0;
        const float t4 = t * 0.25f;               // exact
        const int   j0 = (int)t4;
        const int   j1 = min(j0 + 1, E4_TOT - 1);
        const float qf = t4 - (float)j0;
        const float2 xv = *(const float2*)(x + 2 * pc);
        union { __hip_bfloat16 h; unsigned short u; } x0, x1;
        x0.h = __float2bfloat16(xv.x);
        x1.h = __float2bfloat16(xv.y);
        d[0]  = (unsigned)x0.u | ((unsigned)x1.u << 16);
        d[33] = pkrn(xv.x - __bfloat162float(x0.h), xv.y - __bfloat162float(x1.h));
        d[34] = 0u; d[35] = 0u;
        const float4* r0 = (const float4*)(em0_w + i0 * 20);
        const float4* r1 = (const float4*)(em0_w + i0 * 20 + 20);
        #pragma unroll
        for (int v = 0; v < 5; ++v) {
            float4 a = r0[v], b = r1[v];
            d[1 + 2*v] = pkrn(fmaf(pf, b.x-a.x, a.x), fmaf(pf, b.y-a.y, a.y));
            d[2 + 2*v] = pkrn(fmaf(pf, b.z-a.z, a.z), fmaf(pf, b.w-a.w, a.w));
        }
        const float4* s0 = (const float4*)(em1_w + j0 * 44);
        const float4* s1 = (const float4*)(em1_w + j1 * 44);
        #pragma unroll
        for (int v = 0; v < 11; ++v) {
            float4 a = s0[v], b = s1[v];
            d[11 + 2*v] = pkrn(fmaf(qf, b.x-a.x, a.x), fmaf(qf, b.y-a.y, a.y));
            d[12 + 2*v] = pkrn(fmaf(qf, b.z-a.z, a.z), fmaf(qf, b.w-a.w, a.w));
        }
        uint4* rw = (uint4*)(smem + tid * RS_B);
        #pragma unroll
        for (int ch = 0; ch < 9; ++ch)
            rw[ch] = make_uint4(d[4*ch], d[4*ch+1], d[4*ch+2], d[4*ch+3]);
        rw[9]  = make_uint4(0,0,0,0);
        rw[10] = make_uint4(0,0,0,0);
        rw[11] = make_uint4(0,0,0,0);
    }
    __syncthreads();

    // ---- Layer 0: feat[96] @ W0p -> h1[128] (bf16 to LDS), clamp ----------
    // A-frag: lane row = l&15, k = 8*(l>>4)+e; D: row=(l>>4)*4+r, col=l&15.
    const char* arow = smem + (wv * 64 + c) * RS_B + g * 16;
    bf16x8 a0[4][3];
    #pragma unroll
    for (int mt = 0; mt < 4; ++mt)
        #pragma unroll
        for (int s = 0; s < 3; ++s)
            a0[mt][s] = *(const bf16x8*)(arow + mt * 16 * RS_B + s * 64);

    #pragma unroll
    for (int t = 0; t < 8; ++t) {
        bf16x8 bw[3];
        #pragma unroll
        for (int s = 0; s < 3; ++s)
            bw[s] = *(const bf16x8*)(W0p + ((t*3 + s) << 9) + (lane << 3));
        f32x4 acc[4] = {};
        #pragma unroll
        for (int s = 0; s < 3; ++s)
            #pragma unroll
            for (int mt = 0; mt < 4; ++mt)
                acc[mt] = __builtin_amdgcn_mfma_f32_16x16x32_bf16(a0[mt][s], bw[s], acc[mt], 0, 0, 0);
        const float bb = b0[t*16 + c];
        #pragma unroll
        for (int mt = 0; mt < 4; ++mt)
            #pragma unroll
            for (int r = 0; r < 4; ++r) {
                float v = fminf(fmaxf(acc[mt][r] + bb, 0.0f), 1.0f);
                *(__hip_bfloat16*)(smem + (wv*64 + mt*16 + g*4 + r) * RS_B + (t*16 + c) * 2)
                    = __float2bfloat16(v);
            }
    }
    __syncthreads();

    // ---- Layer 1 + fused W2: h1[128] @ W1p, clamp, dot W2 in-register -----
    bf16x8 a1[4][4];
    #pragma unroll
    for (int mt = 0; mt < 4; ++mt)
        #pragma unroll
        for (int s = 0; s < 4; ++s)
            a1[mt][s] = *(const bf16x8*)(arow + mt * 16 * RS_B + s * 64);

    float zp[16];
    #pragma unroll
    for (int i = 0; i < 16; ++i) zp[i] = 0.0f;

    #pragma unroll
    for (int t = 0; t < 6; ++t) {
        bf16x8 bw[4];
        #pragma unroll
        for (int s = 0; s < 4; ++s)
            bw[s] = *(const bf16x8*)(W1p + ((t*4 + s) << 9) + (lane << 3));
        f32x4 acc[4] = {};
        #pragma unroll
        for (int s = 0; s < 4; ++s)
            #pragma unroll
            for (int mt = 0; mt < 4; ++mt)
                acc[mt] = __builtin_amdgcn_mfma_f32_16x16x32_bf16(a1[mt][s], bw[s], acc[mt], 0, 0, 0);
        const float bb = b1[t*16 + c];
        const float w2 = W2[t*16 + c];
        #pragma unroll
        for (int mt = 0; mt < 4; ++mt)
            #pragma unroll
            for (int r = 0; r < 4; ++r) {
                float v = fminf(fmaxf(acc[mt][r] + bb, 0.0f), 1.0f);
                zp[mt*4 + r] = fmaf(v, w2, zp[mt*4 + r]);
            }
    }

    // ---- Fold-reduce across the 16 c-lanes: lane c ends with row idx c ----
    // Each step: bit-set lanes keep upper half, send lower (and vice versa).
    float f8[8];
    #pragma unroll
    for (int i = 0; i < 8; ++i) {
        float send = (c & 8) ? zp[i]     : zp[i + 8];
        float keep = (c & 8) ? zp[i + 8] : zp[i];
        f8[i] = keep + __shfl_xor(send, 8);
    }
    float f4[4];
    #pragma unroll
    for (int i = 0; i < 4; ++i) {
        float send = (c & 4) ? f8[i]     : f8[i + 4];
        float keep = (c & 4) ? f8[i + 4] : f8[i];
        f4[i] = keep + __shfl_xor(send, 4);
    }
    float f2[2];
    #pragma unroll
    for (int i = 0; i < 2; ++i) {
        float send = (c & 2) ? f4[i]     : f4[i + 2];
        float keep = (c & 2) ? f4[i + 2] : f4[i];
        f2[i] = keep + __shfl_xor(send, 2);
    }
    float send = (c & 1) ? f2[0] : f2[1];
    float keep = (c & 1) ? f2[1] : f2[0];
    float z = keep + __shfl_xor(send, 1);

    z += b2[0];
    z = 1.0f / (1.0f + __expf(-z));
    const int m   = wv * 64 + (c >> 2) * 16 + g * 4 + (c & 3);
    const int pst = blockIdx.x * ROWS + m;
    if (pst < N) out[pst] = z;
}

extern "C" void kernel_launch(void* const* d_in, const int* in_sizes, int n_in,
                              void* d_out, int out_size, void* d_ws, size_t ws_size,
                              hipStream_t stream) {
    const float* x     = (const float*)d_in[0];
    const float* emb   = (const float*)d_in[1];
    const float* em0_w = (const float*)d_in[2];
    const float* em1_w = (const float*)d_in[3];
    const float* W0    = (const float*)d_in[4];
    const float* b0    = (const float*)d_in[5];
    const float* W1    = (const float*)d_in[6];
    const float* b1    = (const float*)d_in[7];
    const float* W2    = (const float*)d_in[8];
    const float* b2    = (const float*)d_in[9];
    float* out = (float*)d_out;
    const int N = in_sizes[1];

    unsigned short* W0p = (unsigned short*)d_ws;   // 12288 bf16
    unsigned short* W1p = W0p + 12288;             // 12288 bf16

    pack_w<<<96, 256, 0, stream>>>(W0, W1, W0p, W1p);
    const int nb = (N + ROWS - 1) / ROWS;
    fused_mlp<<<nb, ROWS, 0, stream>>>(x, emb, em0_w, em1_w, b0, b1, W2, b2,
                                       W0p, W1p, out, N);
}

// Round 5
// 88.429 us; speedup vs baseline: 113.7509x; 1.0753x over previous
//
#include <hip/hip_runtime.h>
#include <hip/hip_bf16.h>

typedef short bf16x8 __attribute__((ext_vector_type(8)));
typedef float f32x4  __attribute__((ext_vector_type(4)));

#define E4_TOT  1643
#define RS_B    272     // 68 dwords == 4 mod 32 -> b128 rows spread across banks
#define ROWS    64      // 1 wave per block; all phases wave-local -> NO barriers

static __device__ __forceinline__ unsigned pkrn(float a, float b) {
    union { __hip_bfloat162 h; unsigned u; } v;
    v.h = __float22bfloat162_rn(float2{a, b});    // v_cvt_pk_bf16_f32
    return v.u;
}
static __device__ __forceinline__ float clamp01(float v) {
    return __builtin_amdgcn_fmed3f(v, 0.0f, 1.0f);
}

// Pack W0/W1 (fp32) into bf16 MFMA B-fragment order:
//   frag(t,s), lane l, elem e  <-  W[k = 32s + 8*(l>>4) + e][n = 16t + (l&15)]
// W0 K padded 66->96. Dekker-x: rows 66,67 duplicate W0 rows 0,1 (x-lo term).
__global__ void pack_w(const float* __restrict__ W0, const float* __restrict__ W1,
                       unsigned short* __restrict__ W0p, unsigned short* __restrict__ W1p)
{
    int id = blockIdx.x * 256 + threadIdx.x;      // [0, 24576)
    int e = id & 7, l = (id >> 3) & 63, f = id >> 9;
    int g = l >> 4, c = l & 15;
    union { __hip_bfloat16 h; unsigned short u; } cv;
    if (f < 24) {                                 // W0p: f = t*3 + s, t<8, s<3
        int s = f % 3, t = f / 3;
        int k = s * 32 + g * 8 + e, n = t * 16 + c;
        float v = (k < 66) ? W0[k * 128 + n]
                : ((k < 68) ? W0[(k - 66) * 128 + n] : 0.0f);
        cv.h = __float2bfloat16(v);
        W0p[id] = cv.u;
    } else {                                      // W1p: f-24 = t*4 + s, t<6, s<4
        int f1 = f - 24;
        int s = f1 & 3, t = f1 >> 2;
        int k = s * 32 + g * 8 + e, n = t * 16 + c;
        cv.h = __float2bfloat16(W1[k * 96 + n]);
        W1p[id - 12288] = cv.u;
    }
}

__global__ __launch_bounds__(64, 2) void fused_mlp(
    const float* __restrict__ x, const float* __restrict__ emb,
    const float* __restrict__ em0_w, const float* __restrict__ em1_w,
    const float* __restrict__ b0, const float* __restrict__ b1,
    const float* __restrict__ W2, const float* __restrict__ b2,
    const unsigned short* __restrict__ W0p, const unsigned short* __restrict__ W1p,
    float* __restrict__ out, int N)
{
    __shared__ __align__(16) char smem[ROWS * RS_B];   // 17408 B -> 9 blocks/CU
    const int lane = threadIdx.x;                 // 64 threads = 1 wave
    const int g    = lane >> 4, c = lane & 15;
    const int p    = blockIdx.x * ROWS + lane;
    const int pc   = min(p, N - 1);               // tail guard (N%64==0 anyway)

    // ---- Phase A: build feature row in regs, store as 12 ds_write_b128 ----
    // layout: [0,1]=bf16(x) [2..21]=em0 [22..65]=em1 [66,67]=x_lo [68..95]=0
    {
        unsigned d[36];
        const float t  = emb[pc];
        const int   i0 = (int)t;                  // i0+1 <= E-1 always
        const float pf = t - (float)i0;
        const float t4 = t * 0.25f;               // exact
        const int   j0 = (int)t4;
        const int   j1 = min(j0 + 1, E4_TOT - 1);
        const float qf = t4 - (float)j0;
        const float2 xv = *(const float2*)(x + 2 * pc);
        union { __hip_bfloat16 h; unsigned short u; } x0, x1;
        x0.h = __float2bfloat16(xv.x);
        x1.h = __float2bfloat16(xv.y);
        d[0]  = (unsigned)x0.u | ((unsigned)x1.u << 16);
        d[33] = pkrn(xv.x - __bfloat162float(x0.h), xv.y - __bfloat162float(x1.h));
        d[34] = 0u; d[35] = 0u;
        const float4* r0 = (const float4*)(em0_w + i0 * 20);
        const float4* r1 = (const float4*)(em0_w + i0 * 20 + 20);
        #pragma unroll
        for (int v = 0; v < 5; ++v) {
            float4 a = r0[v], b = r1[v];
            d[1 + 2*v] = pkrn(fmaf(pf, b.x-a.x, a.x), fmaf(pf, b.y-a.y, a.y));
            d[2 + 2*v] = pkrn(fmaf(pf, b.z-a.z, a.z), fmaf(pf, b.w-a.w, a.w));
        }
        const float4* s0 = (const float4*)(em1_w + j0 * 44);
        const float4* s1 = (const float4*)(em1_w + j1 * 44);
        #pragma unroll
        for (int v = 0; v < 11; ++v) {
            float4 a = s0[v], b = s1[v];
            d[11 + 2*v] = pkrn(fmaf(qf, b.x-a.x, a.x), fmaf(qf, b.y-a.y, a.y));
            d[12 + 2*v] = pkrn(fmaf(qf, b.z-a.z, a.z), fmaf(qf, b.w-a.w, a.w));
        }
        uint4* rw = (uint4*)(smem + lane * RS_B);
        #pragma unroll
        for (int ch = 0; ch < 9; ++ch)
            rw[ch] = make_uint4(d[4*ch], d[4*ch+1], d[4*ch+2], d[4*ch+3]);
        rw[9]  = make_uint4(0,0,0,0);
        rw[10] = make_uint4(0,0,0,0);
        rw[11] = make_uint4(0,0,0,0);
    }
    // no barrier: wave-local LDS; compiler orders via lgkmcnt

    // ---- Layer 0: feat[96] @ W0p -> h1[128] (bf16 to LDS), clamp ----------
    // A-frag: lane row = l&15, k = 8*(l>>4)+e; D: row=(l>>4)*4+r, col=l&15.
    const char* arow = smem + c * RS_B + g * 16;
    bf16x8 a0[4][3];
    #pragma unroll
    for (int mt = 0; mt < 4; ++mt)
        #pragma unroll
        for (int s = 0; s < 3; ++s)
            a0[mt][s] = *(const bf16x8*)(arow + mt * 16 * RS_B + s * 64);

    #pragma unroll
    for (int t = 0; t < 8; ++t) {
        bf16x8 bw[3];
        #pragma unroll
        for (int s = 0; s < 3; ++s)
            bw[s] = *(const bf16x8*)(W0p + ((t*3 + s) << 9) + (lane << 3));
        const float bb = b0[t*16 + c];
        f32x4 acc[4];
        #pragma unroll
        for (int mt = 0; mt < 4; ++mt) acc[mt] = f32x4{bb, bb, bb, bb};
        #pragma unroll
        for (int s = 0; s < 3; ++s)
            #pragma unroll
            for (int mt = 0; mt < 4; ++mt)
                acc[mt] = __builtin_amdgcn_mfma_f32_16x16x32_bf16(a0[mt][s], bw[s], acc[mt], 0, 0, 0);
        #pragma unroll
        for (int mt = 0; mt < 4; ++mt)
            #pragma unroll
            for (int r = 0; r < 4; ++r)
                *(__hip_bfloat16*)(smem + (mt*16 + g*4 + r) * RS_B + (t*16 + c) * 2)
                    = __float2bfloat16(clamp01(acc[mt][r]));
    }

    // ---- Layer 1 + fused W2: h1[128] @ W1p, clamp, dot W2 in-register -----
    bf16x8 a1[4][4];
    #pragma unroll
    for (int mt = 0; mt < 4; ++mt)
        #pragma unroll
        for (int s = 0; s < 4; ++s)
            a1[mt][s] = *(const bf16x8*)(arow + mt * 16 * RS_B + s * 64);

    float zp[16];
    #pragma unroll
    for (int i = 0; i < 16; ++i) zp[i] = 0.0f;

    #pragma unroll
    for (int t = 0; t < 6; ++t) {
        bf16x8 bw[4];
        #pragma unroll
        for (int s = 0; s < 4; ++s)
            bw[s] = *(const bf16x8*)(W1p + ((t*4 + s) << 9) + (lane << 3));
        const float bb = b1[t*16 + c];
        f32x4 acc[4];
        #pragma unroll
        for (int mt = 0; mt < 4; ++mt) acc[mt] = f32x4{bb, bb, bb, bb};
        #pragma unroll
        for (int s = 0; s < 4; ++s)
            #pragma unroll
            for (int mt = 0; mt < 4; ++mt)
                acc[mt] = __builtin_amdgcn_mfma_f32_16x16x32_bf16(a1[mt][s], bw[s], acc[mt], 0, 0, 0);
        const float w2 = W2[t*16 + c];
        #pragma unroll
        for (int mt = 0; mt < 4; ++mt)
            #pragma unroll
            for (int r = 0; r < 4; ++r)
                zp[mt*4 + r] = fmaf(clamp01(acc[mt][r]), w2, zp[mt*4 + r]);
    }

    // ---- Fold-reduce across the 16 c-lanes: lane c ends with row idx c ----
    float f8[8];
    #pragma unroll
    for (int i = 0; i < 8; ++i) {
        float send = (c & 8) ? zp[i]     : zp[i + 8];
        float keep = (c & 8) ? zp[i + 8] : zp[i];
        f8[i] = keep + __shfl_xor(send, 8);
    }
    float f4[4];
    #pragma unroll
    for (int i = 0; i < 4; ++i) {
        float send = (c & 4) ? f8[i]     : f8[i + 4];
        float keep = (c & 4) ? f8[i + 4] : f8[i];
        f4[i] = keep + __shfl_xor(send, 4);
    }
    float f2[2];
    #pragma unroll
    for (int i = 0; i < 2; ++i) {
        float send = (c & 2) ? f4[i]     : f4[i + 2];
        float keep = (c & 2) ? f4[i + 2] : f4[i];
        f2[i] = keep + __shfl_xor(send, 2);
    }
    float send = (c & 1) ? f2[0] : f2[1];
    float keep = (c & 1) ? f2[1] : f2[0];
    float z = keep + __shfl_xor(send, 1);

    z += b2[0];
    z = 1.0f / (1.0f + __expf(-z));
    const int m   = (c >> 2) * 16 + g * 4 + (c & 3);
    const int pst = blockIdx.x * ROWS + m;
    if (pst < N) out[pst] = z;
}

extern "C" void kernel_launch(void* const* d_in, const int* in_sizes, int n_in,
                              void* d_out, int out_size, void* d_ws, size_t ws_size,
                              hipStream_t stream) {
    const float* x     = (const float*)d_in[0];
    const float* emb   = (const float*)d_in[1];
    const float* em0_w = (const float*)d_in[2];
    const float* em1_w = (const float*)d_in[3];
    const float* W0    = (const float*)d_in[4];
    const float* b0    = (const float*)d_in[5];
    const float* W1    = (const float*)d_in[6];
    const float* b1    = (const float*)d_in[7];
    const float* W2    = (const float*)d_in[8];
    const float* b2    = (const float*)d_in[9];
    float* out = (float*)d_out;
    const int N = in_sizes[1];

    unsigned short* W0p = (unsigned short*)d_ws;   // 12288 bf16
    unsigned short* W1p = W0p + 12288;             // 12288 bf16

    pack_w<<<96, 256, 0, stream>>>(W0, W1, W0p, W1p);
    const int nb = (N + ROWS - 1) / ROWS;
    fused_mlp<<<nb, ROWS, 0, stream>>>(x, emb, em0_w, em1_w, b0, b1, W2, b2,
                                       W0p, W1p, out, N);
}

// Round 6
// 82.487 us; speedup vs baseline: 121.9457x; 1.0720x over previous
//
#include <hip/hip_runtime.h>
#include <hip/hip_bf16.h>

typedef short bf16x8 __attribute__((ext_vector_type(8)));
typedef float f32x4  __attribute__((ext_vector_type(4)));

#define E_TOT   6572
#define E4_TOT  1643
#define RSDW    68      // LDS row stride in dwords (272 B): b128 rows spread banks

// d_ws layout (ushort indices): [0,12288) W0p | [12288,24576) W1p |
// [24576,182304) em0b [6572][24] | [182304,261168) em1b [1643][48]
#define EM0B_OFF 24576
#define EM1B_OFF 182304

static __device__ __forceinline__ unsigned pkrn(float a, float b) {
    union { __hip_bfloat162 h; unsigned u; } v;
    v.h = __float22bfloat162_rn(float2{a, b});    // v_cvt_pk_bf16_f32
    return v.u;
}
static __device__ __forceinline__ float clamp01(float v) {
    return __builtin_amdgcn_fmed3f(v, 0.0f, 1.0f);
}
// lerp two packed-bf16 dwords (a=row0, b=row1) with fp32 weight p -> packed bf16
static __device__ __forceinline__ unsigned lerp_dw(unsigned a, unsigned b, float p) {
    float alo = __uint_as_float(a << 16);
    float ahi = __uint_as_float(a & 0xffff0000u);
    float blo = __uint_as_float(b << 16);
    float bhi = __uint_as_float(b & 0xffff0000u);
    return pkrn(fmaf(p, blo - alo, alo), fmaf(p, bhi - ahi, ahi));
}

// One kernel packs everything: W0p/W1p in MFMA fragment order
//   frag(t,s), lane l, elem e  <-  W[k = 32s + 8*(l>>4) + e][n = 16t + (l&15)]
// (W0 K padded 66->96; rows 66,67 duplicate rows 0,1 for the Dekker-x term)
// plus bf16 copies of em0_w (rows padded 20->24) and em1_w (44->48).
__global__ void pack_all(const float* __restrict__ W0, const float* __restrict__ W1,
                         const float* __restrict__ em0_w, const float* __restrict__ em1_w,
                         unsigned short* __restrict__ ws)
{
    int id = blockIdx.x * 256 + threadIdx.x;
    if (id >= 261168) return;
    union { __hip_bfloat16 h; unsigned short u; } cv;
    if (id < 12288) {                              // W0p: f = t*3+s, t<8, s<3
        int e = id & 7, l = (id >> 3) & 63, f = id >> 9;
        int g = l >> 4, c = l & 15;
        int s = f % 3, t = f / 3;
        int k = s * 32 + g * 8 + e, n = t * 16 + c;
        float v = (k < 66) ? W0[k * 128 + n]
                : ((k < 68) ? W0[(k - 66) * 128 + n] : 0.0f);
        cv.h = __float2bfloat16(v);
        ws[id] = cv.u;
    } else if (id < 24576) {                       // W1p: f = t*4+s, t<6, s<4
        int id1 = id - 12288;
        int e = id1 & 7, l = (id1 >> 3) & 63, f = id1 >> 9;
        int g = l >> 4, c = l & 15;
        int s = f & 3, t = f >> 2;
        int k = s * 32 + g * 8 + e, n = t * 16 + c;
        cv.h = __float2bfloat16(W1[k * 96 + n]);
        ws[id] = cv.u;
    } else if (id < EM1B_OFF) {                    // em0b [6572][24]
        int q = id - EM0B_OFF;
        int row = q / 24, col = q - row * 24;
        cv.h = __float2bfloat16(col < 20 ? em0_w[row * 20 + col] : 0.0f);
        ws[id] = cv.u;
    } else {                                       // em1b [1643][48]
        int q = id - EM1B_OFF;
        int row = q / 48, col = q - row * 48;
        cv.h = __float2bfloat16(col < 44 ? em1_w[row * 44 + col] : 0.0f);
        ws[id] = cv.u;
    }
}

// Swapped-operand MFMA MLP: A = W^T (packed), B = features^T / h1^T.
// D[out][pt]: lane (g,c) holds rows out=(16t+4g+r), col pt=(16mt+c).
__global__ __launch_bounds__(64, 2) void fused_mlp(
    const float* __restrict__ x, const float* __restrict__ emb,
    const float* __restrict__ b0, const float* __restrict__ b1,
    const float* __restrict__ W2, const float* __restrict__ b2,
    const unsigned short* __restrict__ ws,
    float* __restrict__ out, int N)
{
    __shared__ __align__(16) char smem[64 * RSDW * 4];  // 17408 B: features -> h1T
    const unsigned short* W0p  = ws;
    const unsigned short* W1p  = ws + 12288;
    const unsigned short* em0b = ws + EM0B_OFF;
    const unsigned short* em1b = ws + EM1B_OFF;

    const int lane = threadIdx.x;                 // one wave per block
    const int g    = lane >> 4, c = lane & 15;
    const int p    = blockIdx.x * 64 + lane;
    const int pc   = min(p, N - 1);

    // ---- Phase A: gather bf16 regions, lerp, write feature row ------------
    // feature k-layout: [0,1]=bf16(x) [2..21]=em0 [22..65]=em1 [66,67]=x_lo [68..95]=0
    {
        const float t  = emb[pc];
        const int   i0 = (int)t;                  // i0 <= 6570 -> i0+1 valid
        const float pf = t - (float)i0;
        const float t4 = t * 0.25f;               // exact
        const int   j0 = (int)t4;
        int   jbase = j0;  float qf = t4 - (float)j0;
        if (j0 >= E4_TOT - 1) { jbase = E4_TOT - 2; qf = 1.0f; }  // rows(j0,j0)==lerp(j0-1,j0,1)

        uint4 e0[6];                              // em0b rows i0,i0+1 (2 x 48B)
        const uint4* R0 = (const uint4*)(em0b + i0 * 24);
        #pragma unroll
        for (int v = 0; v < 6; ++v) e0[v] = R0[v];
        uint4 e1[12];                             // em1b rows jbase,jbase+1 (2 x 96B)
        const uint4* R1 = (const uint4*)(em1b + jbase * 48);
        #pragma unroll
        for (int v = 0; v < 12; ++v) e1[v] = R1[v];

        const float2 xv = *(const float2*)(x + 2 * pc);
        union { __hip_bfloat16 h; unsigned short u; } x0, x1;
        x0.h = __float2bfloat16(xv.x);
        x1.h = __float2bfloat16(xv.y);

        unsigned d[48];
        d[0]  = (unsigned)x0.u | ((unsigned)x1.u << 16);
        const unsigned* a0dw = (const unsigned*)e0;     // [0..11]=row0, [12..23]=row1
        #pragma unroll
        for (int i = 0; i < 10; ++i)                    // em0 dims 0..19
            d[1 + i] = lerp_dw(a0dw[i], a0dw[12 + i], pf);
        const unsigned* b0dw = (const unsigned*)e1;     // [0..23]=row0, [24..47]=row1
        #pragma unroll
        for (int i = 0; i < 22; ++i)                    // em1 dims 0..43
            d[11 + i] = lerp_dw(b0dw[i], b0dw[24 + i], qf);
        d[33] = pkrn(xv.x - __bfloat162float(x0.h), xv.y - __bfloat162float(x1.h));
        #pragma unroll
        for (int i = 34; i < 48; ++i) d[i] = 0u;

        uint4* rw = (uint4*)(smem + lane * (RSDW * 4));
        #pragma unroll
        for (int ch = 0; ch < 12; ++ch)
            rw[ch] = make_uint4(d[4*ch], d[4*ch+1], d[4*ch+2], d[4*ch+3]);
    }

    // ---- load all feature B-frags to regs (frees LDS region for h1T) ------
    // B-frag(mt,s): lane (g,c) holds feat[k=32s+8g+e][pt=16mt+c]
    bf16x8 a0[4][3];
    #pragma unroll
    for (int mt = 0; mt < 4; ++mt)
        #pragma unroll
        for (int s = 0; s < 3; ++s)
            a0[mt][s] = *(const bf16x8*)(smem + ((16*mt + c) * RSDW + 16*s + 4*g) * 4);

    // ---- Layer 0 (swapped): D0[out][pt]; h1 -> LDS h1T[pt][out] as b64 ----
    #pragma unroll
    for (int t = 0; t < 8; ++t) {
        bf16x8 bw[3];
        #pragma unroll
        for (int s = 0; s < 3; ++s)
            bw[s] = *(const bf16x8*)(W0p + ((t*3 + s) << 9) + (lane << 3));
        const float4 b0v = *(const float4*)(b0 + t*16 + g*4);   // b0[16t+4g+r]
        f32x4 acc[4];
        #pragma unroll
        for (int mt = 0; mt < 4; ++mt) acc[mt] = f32x4{b0v.x, b0v.y, b0v.z, b0v.w};
        #pragma unroll
        for (int s = 0; s < 3; ++s)
            #pragma unroll
            for (int mt = 0; mt < 4; ++mt)
                acc[mt] = __builtin_amdgcn_mfma_f32_16x16x32_bf16(bw[s], a0[mt][s], acc[mt], 0, 0, 0);
        #pragma unroll
        for (int mt = 0; mt < 4; ++mt) {
            unsigned P0 = pkrn(clamp01(acc[mt][0]), clamp01(acc[mt][1]));  // outs 16t+4g+0,1
            unsigned P1 = pkrn(clamp01(acc[mt][2]), clamp01(acc[mt][3]));  // outs 16t+4g+2,3
            *(uint2*)(smem + ((16*mt + c) * RSDW + 8*t + 2*g) * 4) = make_uint2(P0, P1);
        }
    }
    __syncthreads();   // single-wave: cheap; guarantees h1T writes visible

    // ---- load h1 B-frags: hb[s1][mt] = h1[k=32s1+8g+e][pt=16mt+c] ---------
    bf16x8 hb[4][4];
    #pragma unroll
    for (int s1 = 0; s1 < 4; ++s1)
        #pragma unroll
        for (int mt = 0; mt < 4; ++mt)
            hb[s1][mt] = *(const bf16x8*)(smem + ((16*mt + c) * RSDW + 16*s1 + 4*g) * 4);

    // ---- Layer 1 (swapped) + fused W2 ------------------------------------
    float zp[4] = {0.f, 0.f, 0.f, 0.f};
    #pragma unroll
    for (int t1 = 0; t1 < 6; ++t1) {
        bf16x8 bw1[4];
        #pragma unroll
        for (int s1 = 0; s1 < 4; ++s1)
            bw1[s1] = *(const bf16x8*)(W1p + ((t1*4 + s1) << 9) + (lane << 3));
        const float4 b1v = *(const float4*)(b1 + t1*16 + g*4);
        f32x4 acc[4];
        #pragma unroll
        for (int mt = 0; mt < 4; ++mt) acc[mt] = f32x4{b1v.x, b1v.y, b1v.z, b1v.w};
        #pragma unroll
        for (int s1 = 0; s1 < 4; ++s1)
            #pragma unroll
            for (int mt = 0; mt < 4; ++mt)
                acc[mt] = __builtin_amdgcn_mfma_f32_16x16x32_bf16(bw1[s1], hb[s1][mt], acc[mt], 0, 0, 0);
        const float4 w2v = *(const float4*)(W2 + t1*16 + g*4);  // W2[16t1+4g+r]
        #pragma unroll
        for (int mt = 0; mt < 4; ++mt) {
            zp[mt] = fmaf(clamp01(acc[mt][0]), w2v.x, zp[mt]);
            zp[mt] = fmaf(clamp01(acc[mt][1]), w2v.y, zp[mt]);
            zp[mt] = fmaf(clamp01(acc[mt][2]), w2v.z, zp[mt]);
            zp[mt] = fmaf(clamp01(acc[mt][3]), w2v.w, zp[mt]);
        }
    }

    // ---- reduce over g (4 lanes per pt-column), select, sigmoid, store ----
    float zr[4];
    #pragma unroll
    for (int mt = 0; mt < 4; ++mt) {
        float v = zp[mt];
        v += __shfl_xor(v, 16);
        v += __shfl_xor(v, 32);
        zr[mt] = v;                               // full z for pt=16mt+c, all lanes
    }
    float z = (g == 0) ? zr[0] : (g == 1) ? zr[1] : (g == 2) ? zr[2] : zr[3];
    z += b2[0];
    z = 1.0f / (1.0f + __expf(-z));
    if (p < N) out[p] = z;                        // pt = 16g+c = lane: coalesced
}

extern "C" void kernel_launch(void* const* d_in, const int* in_sizes, int n_in,
                              void* d_out, int out_size, void* d_ws, size_t ws_size,
                              hipStream_t stream) {
    const float* x     = (const float*)d_in[0];
    const float* emb   = (const float*)d_in[1];
    const float* em0_w = (const float*)d_in[2];
    const float* em1_w = (const float*)d_in[3];
    const float* W0    = (const float*)d_in[4];
    const float* b0    = (const float*)d_in[5];
    const float* W1    = (const float*)d_in[6];
    const float* b1    = (const float*)d_in[7];
    const float* W2    = (const float*)d_in[8];
    const float* b2    = (const float*)d_in[9];
    float* out = (float*)d_out;
    const int N = in_sizes[1];

    unsigned short* ws = (unsigned short*)d_ws;   // 522336 B used

    pack_all<<<1021, 256, 0, stream>>>(W0, W1, em0_w, em1_w, ws);
    const int nb = (N + 63) / 64;
    fused_mlp<<<nb, 64, 0, stream>>>(x, emb, b0, b1, W2, b2, ws, out, N);
}